// Round 1
// baseline (247.252 us; speedup 1.0000x reference)
//
#include <hip/hip_runtime.h>
#include <hip/hip_bf16.h>

typedef __attribute__((ext_vector_type(4))) float f32x4;
typedef __attribute__((ext_vector_type(8))) short short8;

#define P_TOT 16384
#define NCO 128
#define EPS 1e-5f
// log2(e) / sqrt(128)
#define ALPHA 0.12752269f

__device__ __forceinline__ unsigned short f2bf(float f) {
  union { float f; unsigned u; } v; v.f = f;
  unsigned r = v.u + 0x7FFFu + ((v.u >> 16) & 1u);
  return (unsigned short)(r >> 16);
}
__device__ __forceinline__ float bf2f(unsigned short h) {
  union { unsigned u; float f; } v; v.u = ((unsigned)h) << 16;
  return v.f;
}

// ---------------------------------------------------------------------------
// 1x1 conv (GEMM) + BatchNorm(eval) + ReLU, f32 compute, bf16 [b][p][c] out.
// Block: 64 pixels x 128 co. Thread: 8 px x 4 co = 32 acc.
// ---------------------------------------------------------------------------
__global__ __launch_bounds__(256) void proj_kernel(
    const float* __restrict__ X,    // [B][Cin][P]
    const float* __restrict__ Wm,   // [128][Cin]
    const float* __restrict__ gamma, const float* __restrict__ beta,
    const float* __restrict__ mean, const float* __restrict__ var,
    unsigned short* __restrict__ out,  // [B][P][128] bf16
    int Cin)
{
  __shared__ float Ws[64][128];  // [c][co] 32 KB
  __shared__ float Xs[64][64];   // [c][px] 16 KB
  const int t = threadIdx.x;
  const int b = blockIdx.y;
  const int pbase = blockIdx.x * 64;
  const int co0 = (t & 31) * 4;
  const int px0 = (t >> 5) * 8;

  float acc[8][4];
#pragma unroll
  for (int i = 0; i < 8; ++i)
#pragma unroll
    for (int j = 0; j < 4; ++j) acc[i][j] = 0.f;

  const float* Xb = X + (size_t)b * Cin * P_TOT + pbase;

  for (int cc = 0; cc < Cin; cc += 64) {
    __syncthreads();
#pragma unroll
    for (int i = 0; i < 16; ++i) {   // 64x64 f32 X tile, coalesced
      int e = t + 256 * i;
      Xs[e >> 6][e & 63] = Xb[(size_t)(cc + (e >> 6)) * P_TOT + (e & 63)];
    }
#pragma unroll
    for (int i = 0; i < 32; ++i) {   // 64x128 f32 W tile (transposed store)
      int e = t + 256 * i;
      int co = e & 127, c = e >> 7;
      Ws[c][co] = Wm[(size_t)co * Cin + cc + c];
    }
    __syncthreads();
#pragma unroll 4
    for (int c = 0; c < 64; ++c) {
      f32x4 w4 = *(const f32x4*)&Ws[c][co0];
      f32x4 x0 = *(const f32x4*)&Xs[c][px0];
      f32x4 x1 = *(const f32x4*)&Xs[c][px0 + 4];
#pragma unroll
      for (int j = 0; j < 4; ++j) {
        acc[0][j] = fmaf(x0[0], w4[j], acc[0][j]);
        acc[1][j] = fmaf(x0[1], w4[j], acc[1][j]);
        acc[2][j] = fmaf(x0[2], w4[j], acc[2][j]);
        acc[3][j] = fmaf(x0[3], w4[j], acc[3][j]);
        acc[4][j] = fmaf(x1[0], w4[j], acc[4][j]);
        acc[5][j] = fmaf(x1[1], w4[j], acc[5][j]);
        acc[6][j] = fmaf(x1[2], w4[j], acc[6][j]);
        acc[7][j] = fmaf(x1[3], w4[j], acc[7][j]);
      }
    }
  }

  f32x4 g4 = *(const f32x4*)&gamma[co0];
  f32x4 b4 = *(const f32x4*)&beta[co0];
  f32x4 m4 = *(const f32x4*)&mean[co0];
  f32x4 v4 = *(const f32x4*)&var[co0];
  float sc[4], sh[4];
#pragma unroll
  for (int j = 0; j < 4; ++j) {
    sc[j] = g4[j] / sqrtf(v4[j] + EPS);
    sh[j] = b4[j] - m4[j] * sc[j];
  }
  unsigned short* ob = out + ((size_t)b * P_TOT + pbase + px0) * NCO + co0;
#pragma unroll
  for (int i = 0; i < 8; ++i) {
    float y0 = fmaxf(acc[i][0] * sc[0] + sh[0], 0.f);
    float y1 = fmaxf(acc[i][1] * sc[1] + sh[1], 0.f);
    float y2 = fmaxf(acc[i][2] * sc[2] + sh[2], 0.f);
    float y3 = fmaxf(acc[i][3] * sc[3] + sh[3], 0.f);
    uint2 pk;
    pk.x = (unsigned)f2bf(y0) | ((unsigned)f2bf(y1) << 16);
    pk.y = (unsigned)f2bf(y2) | ((unsigned)f2bf(y3) << 16);
    *(uint2*)(ob + (size_t)i * NCO) = pk;
  }
}

// ---------------------------------------------------------------------------
// Block-diagonal flash attention (q=image_proj, k=v=lidar_proj) + blend.
// Block = 4 waves x 16 q-rows = 64 q-rows of one 2048-px chunk.
// ---------------------------------------------------------------------------
__global__ __launch_bounds__(256) void attn_kernel(
    const unsigned short* __restrict__ Lp,  // [B][P][128] bf16 (k = v)
    const unsigned short* __restrict__ Ip,  // [B][P][128] bf16 (q)
    const float* __restrict__ mw,           // [2]
    float* __restrict__ out)                // [B][128][P] f32
{
  __shared__ __align__(16) char smem[51200];
  unsigned short (*Kt)[136] = (unsigned short (*)[136])smem;          // 64x136 bf16
  unsigned short (*Vt)[64]  = (unsigned short (*)[64])(smem + 17408); // 128x64 bf16 (kp xor-swizzled)

  const int t = threadIdx.x;
  const int wid = t >> 6;
  const int lane = t & 63;
  const int l15 = lane & 15;
  const int g = lane >> 4;
  unsigned short* Pw = (unsigned short*)(smem + 33792) + wid * (16 * 136);

  const int b = blockIdx.z;
  const int chunk = blockIdx.y;
  const int pq0 = chunk * 2048 + blockIdx.x * 64;

  // Q fragments (A operand, rows = 16 q-pixels of this wave), held in regs
  short8 qf[4];
  const unsigned short* Qb =
      Ip + ((size_t)b * P_TOT + pq0 + wid * 16 + l15) * NCO + g * 8;
#pragma unroll
  for (int kk = 0; kk < 4; ++kk) qf[kk] = *(const short8*)(Qb + kk * 32);

  f32x4 o[8];
#pragma unroll
  for (int i = 0; i < 8; ++i) o[i] = (f32x4){0.f, 0.f, 0.f, 0.f};
  float m[4], lsum[4];
#pragma unroll
  for (int r = 0; r < 4; ++r) { m[r] = -1e30f; lsum[r] = 0.f; }

  const unsigned short* Kgbase = Lp + ((size_t)b * P_TOT + chunk * 2048) * NCO;

  for (int kt = 0; kt < 32; ++kt) {
    __syncthreads();
    {  // stage K-tile: Kt[kp][c] linear + Vt[c][kp^swz] transposed
      const unsigned short* Kg = Kgbase + (size_t)kt * 64 * NCO;
      const int c0 = (t & 15) * 8;
      const int sw = (t & 7) << 3;  // ((c0>>3)&7)<<3
#pragma unroll
      for (int i = 0; i < 4; ++i) {
        int kp = (t >> 4) + 16 * i;
        short8 kv = *(const short8*)(Kg + (size_t)kp * NCO + c0);
        *(short8*)&Kt[kp][c0] = kv;
        int kps = kp ^ sw;
#pragma unroll
        for (int j = 0; j < 8; ++j) Vt[c0 + j][kps] = (unsigned short)kv[j];
      }
    }
    __syncthreads();

    // S = Q K^T  (16 q x 64 kp per wave)
    f32x4 s[4];
#pragma unroll
    for (int nt = 0; nt < 4; ++nt) s[nt] = (f32x4){0.f, 0.f, 0.f, 0.f};
#pragma unroll
    for (int kk = 0; kk < 4; ++kk) {
#pragma unroll
      for (int nt = 0; nt < 4; ++nt) {
        short8 bf = *(const short8*)&Kt[nt * 16 + l15][kk * 32 + g * 8];
        s[nt] = __builtin_amdgcn_mfma_f32_16x16x32_bf16(qf[kk], bf, s[nt], 0, 0, 0);
      }
    }

    // online softmax (rows live on 16 consecutive lanes)
    float f[4];
#pragma unroll
    for (int r = 0; r < 4; ++r) {
      float v = fmaxf(fmaxf(s[0][r], s[1][r]), fmaxf(s[2][r], s[3][r]));
      v = fmaxf(v, __shfl_xor(v, 1));
      v = fmaxf(v, __shfl_xor(v, 2));
      v = fmaxf(v, __shfl_xor(v, 4));
      v = fmaxf(v, __shfl_xor(v, 8));
      float mn = fmaxf(m[r], v * ALPHA);
      f[r] = exp2f(m[r] - mn);
      m[r] = mn;
      float rs = 0.f;
#pragma unroll
      for (int nt = 0; nt < 4; ++nt) {
        float p = exp2f(s[nt][r] * ALPHA - mn);
        rs += p;
        Pw[(4 * g + r) * 136 + nt * 16 + l15] = f2bf(p);
      }
      rs += __shfl_xor(rs, 1);
      rs += __shfl_xor(rs, 2);
      rs += __shfl_xor(rs, 4);
      rs += __shfl_xor(rs, 8);
      lsum[r] = lsum[r] * f[r] + rs;
#pragma unroll
      for (int ct = 0; ct < 8; ++ct) o[ct][r] *= f[r];
    }

    // O += P * V
#pragma unroll
    for (int kk2 = 0; kk2 < 2; ++kk2) {
      short8 af = *(const short8*)(Pw + l15 * 136 + kk2 * 32 + g * 8);
#pragma unroll
      for (int ct = 0; ct < 8; ++ct) {
        int c = ct * 16 + l15;
        int kb = (kk2 * 32 + g * 8) ^ (((c >> 3) & 7) << 3);
        short8 bf = *(const short8*)&Vt[c][kb];
        o[ct] = __builtin_amdgcn_mfma_f32_16x16x32_bf16(af, bf, o[ct], 0, 0, 0);
      }
    }
  }

  // modality softmax
  float a0 = mw[0], a1 = mw[1];
  float mx = fmaxf(a0, a1);
  float e0 = exp2f((a0 - mx) * 1.442695041f);
  float e1 = exp2f((a1 - mx) * 1.442695041f);
  float w0 = e0 / (e0 + e1), w1 = e1 / (e0 + e1);

  __syncthreads();  // done with Kt/Vt/Pw, reuse as transpose buffer
  float (*T)[68] = (float (*)[68])smem;  // [c][q] 128x68 f32
  const unsigned short* Ib = Ip + ((size_t)b * P_TOT + pq0) * NCO;
#pragma unroll
  for (int r = 0; r < 4; ++r) {
    float inv = w1 / lsum[r];
    int q = wid * 16 + 4 * g + r;
#pragma unroll
    for (int ct = 0; ct < 8; ++ct) {
      int c = ct * 16 + l15;
      float img = bf2f(Ib[(size_t)q * NCO + c]);
      T[c][q] = w0 * img + inv * o[ct][r];
    }
  }
  __syncthreads();
  {
    int c = t >> 1, q0 = (t & 1) * 32;
    float* Ob = out + ((size_t)b * NCO + c) * P_TOT + pq0 + q0;
#pragma unroll
    for (int i = 0; i < 8; ++i)
      *(f32x4*)(Ob + 4 * i) = *(const f32x4*)&T[c][q0 + 4 * i];
  }
}

extern "C" void kernel_launch(void* const* d_in, const int* in_sizes, int n_in,
                              void* d_out, int out_size, void* d_ws, size_t ws_size,
                              hipStream_t stream) {
  const float* lidar = (const float*)d_in[0];
  const float* image = (const float*)d_in[1];
  const float* lw = (const float*)d_in[2];
  const float* lg = (const float*)d_in[3];
  const float* lb = (const float*)d_in[4];
  const float* lm = (const float*)d_in[5];
  const float* lv = (const float*)d_in[6];
  const float* iw = (const float*)d_in[7];
  const float* ig = (const float*)d_in[8];
  const float* ibt = (const float*)d_in[9];
  const float* im = (const float*)d_in[10];
  const float* iv = (const float*)d_in[11];
  const float* mw = (const float*)d_in[12];

  unsigned short* Lp = (unsigned short*)d_ws;                    // [2][16384][128] bf16
  unsigned short* Ip = Lp + (size_t)2 * P_TOT * NCO;             // [2][16384][128] bf16

  dim3 gp(P_TOT / 64, 2);
  proj_kernel<<<gp, 256, 0, stream>>>(lidar, lw, lg, lb, lm, lv, Lp, 256);
  proj_kernel<<<gp, 256, 0, stream>>>(image, iw, ig, ibt, im, iv, Ip, 512);

  dim3 ga(2048 / 64, 8, 2);
  attn_kernel<<<ga, 256, 0, stream>>>(Lp, Ip, mw, (float*)d_out);
}

// Round 2
// 201.474 us; speedup vs baseline: 1.2272x; 1.2272x over previous
//
#include <hip/hip_runtime.h>
#include <hip/hip_bf16.h>

typedef __attribute__((ext_vector_type(4))) float f32x4;
typedef __attribute__((ext_vector_type(8))) short short8;

#define P_TOT 16384
#define NCO 128
#define EPS 1e-5f
// log2(e) / sqrt(128)
#define ALPHA 0.12752269f

__device__ __forceinline__ unsigned short f2bf(float f) {
  union { float f; unsigned u; } v; v.f = f;
  unsigned r = v.u + 0x7FFFu + ((v.u >> 16) & 1u);
  return (unsigned short)(r >> 16);
}
__device__ __forceinline__ float bf2f(unsigned short h) {
  union { unsigned u; float f; } v; v.u = ((unsigned)h) << 16;
  return v.f;
}
__device__ __forceinline__ unsigned cvtpk_bf16(float lo, float hi) {
  unsigned r;
  asm("v_cvt_pk_bf16_f32 %0, %1, %2" : "=v"(r) : "v"(lo), "v"(hi));
  return r;
}
__device__ __forceinline__ void gload16(const void* g, void* l) {
  __builtin_amdgcn_global_load_lds(
      (const __attribute__((address_space(1))) unsigned*)g,
      (__attribute__((address_space(3))) unsigned*)l, 16, 0, 0);
}

// ---------------------------------------------------------------------------
// 1x1 conv (GEMM) + BatchNorm(eval) + ReLU, f32 compute.
// out: bf16 [b][p][c]. out2 (optional): bf16 [b][c][p] (transposed copy).
// Block: 64 pixels x 128 co. Thread: 8 px x 4 co = 32 acc.
// ---------------------------------------------------------------------------
__global__ __launch_bounds__(256) void proj_kernel(
    const float* __restrict__ X,    // [B][Cin][P]
    const float* __restrict__ Wm,   // [128][Cin]
    const float* __restrict__ gamma, const float* __restrict__ beta,
    const float* __restrict__ mean, const float* __restrict__ var,
    unsigned short* __restrict__ out,   // [B][P][128] bf16
    unsigned short* __restrict__ out2,  // [B][128][P] bf16 or nullptr
    int Cin)
{
  __shared__ float Ws[64][128];  // [c][co] 32 KB
  __shared__ float Xs[64][64];   // [c][px] 16 KB
  const int t = threadIdx.x;
  const int b = blockIdx.y;
  const int pbase = blockIdx.x * 64;
  const int co0 = (t & 31) * 4;
  const int px0 = (t >> 5) * 8;

  float acc[8][4];
#pragma unroll
  for (int i = 0; i < 8; ++i)
#pragma unroll
    for (int j = 0; j < 4; ++j) acc[i][j] = 0.f;

  const float* Xb = X + (size_t)b * Cin * P_TOT + pbase;

  for (int cc = 0; cc < Cin; cc += 64) {
    __syncthreads();
#pragma unroll
    for (int i = 0; i < 16; ++i) {   // 64x64 f32 X tile, coalesced
      int e = t + 256 * i;
      Xs[e >> 6][e & 63] = Xb[(size_t)(cc + (e >> 6)) * P_TOT + (e & 63)];
    }
#pragma unroll
    for (int i = 0; i < 32; ++i) {   // 64x128 f32 W tile (transposed store)
      int e = t + 256 * i;
      int co = e & 127, c = e >> 7;
      Ws[c][co] = Wm[(size_t)co * Cin + cc + c];
    }
    __syncthreads();
#pragma unroll 4
    for (int c = 0; c < 64; ++c) {
      f32x4 w4 = *(const f32x4*)&Ws[c][co0];
      f32x4 x0 = *(const f32x4*)&Xs[c][px0];
      f32x4 x1 = *(const f32x4*)&Xs[c][px0 + 4];
#pragma unroll
      for (int j = 0; j < 4; ++j) {
        acc[0][j] = fmaf(x0[0], w4[j], acc[0][j]);
        acc[1][j] = fmaf(x0[1], w4[j], acc[1][j]);
        acc[2][j] = fmaf(x0[2], w4[j], acc[2][j]);
        acc[3][j] = fmaf(x0[3], w4[j], acc[3][j]);
        acc[4][j] = fmaf(x1[0], w4[j], acc[4][j]);
        acc[5][j] = fmaf(x1[1], w4[j], acc[5][j]);
        acc[6][j] = fmaf(x1[2], w4[j], acc[6][j]);
        acc[7][j] = fmaf(x1[3], w4[j], acc[7][j]);
      }
    }
  }

  f32x4 g4 = *(const f32x4*)&gamma[co0];
  f32x4 b4 = *(const f32x4*)&beta[co0];
  f32x4 m4 = *(const f32x4*)&mean[co0];
  f32x4 v4 = *(const f32x4*)&var[co0];
  float sc[4], sh[4];
#pragma unroll
  for (int j = 0; j < 4; ++j) {
    sc[j] = g4[j] / sqrtf(v4[j] + EPS);
    sh[j] = b4[j] - m4[j] * sc[j];
  }
  unsigned short ybf[8][4];
  unsigned short* ob = out + ((size_t)b * P_TOT + pbase + px0) * NCO + co0;
#pragma unroll
  for (int i = 0; i < 8; ++i) {
    uint2 pk;
#pragma unroll
    for (int j = 0; j < 4; ++j)
      ybf[i][j] = f2bf(fmaxf(acc[i][j] * sc[j] + sh[j], 0.f));
    pk.x = (unsigned)ybf[i][0] | ((unsigned)ybf[i][1] << 16);
    pk.y = (unsigned)ybf[i][2] | ((unsigned)ybf[i][3] << 16);
    *(uint2*)(ob + (size_t)i * NCO) = pk;
  }
  if (out2) {
#pragma unroll
    for (int j = 0; j < 4; ++j) {
      uint4 pj;
      pj.x = (unsigned)ybf[0][j] | ((unsigned)ybf[1][j] << 16);
      pj.y = (unsigned)ybf[2][j] | ((unsigned)ybf[3][j] << 16);
      pj.z = (unsigned)ybf[4][j] | ((unsigned)ybf[5][j] << 16);
      pj.w = (unsigned)ybf[6][j] | ((unsigned)ybf[7][j] << 16);
      *(uint4*)(out2 + ((size_t)b * NCO + co0 + j) * P_TOT + pbase + px0) = pj;
    }
  }
}

// ---------------------------------------------------------------------------
// Block-diagonal flash attention (q=image_proj, k=v=lidar_proj) + blend.
// Swapped QK^T (S^T = K*Q^T) with pi-permuted K rows so softmax + PV A-frag
// are fully in-lane. XOR-swizzled LDS tiles staged via global_load_lds with
// pre-swizzled global source. 4 waves x 32 q = 128 q/block; 256 blocks.
// ---------------------------------------------------------------------------
__global__ __launch_bounds__(256) void attn_kernel(
    const unsigned short* __restrict__ Lp,  // [B][P][128] bf16 (K rows)
    const unsigned short* __restrict__ Ip,  // [B][P][128] bf16 (Q rows)
    const unsigned short* __restrict__ Vg,  // [B][128][P] bf16 (V cols)
    const float* __restrict__ mw,           // [2]
    float* __restrict__ out)                // [B][128][P] f32
{
  // [0,32768): Kt[2][64][256B]   [32768,65536): Vt[2][128][128B]
  // epilogue reuse: T[64][132] f32 (33792 B)
  __shared__ __align__(16) char smem[65536];

  const int t = threadIdx.x;
  const int w = t >> 6, l = t & 63;
  const int l15 = l & 15, g = l >> 4;
  const int b = blockIdx.z, chunk = blockIdx.y;
  const int pq0 = chunk * 2048 + blockIdx.x * 128;  // block pixel base
  const int qw = pq0 + w * 32;                      // wave q base

  // ---- Q fragments (held in regs; same data serves as B-operand of S^T)
  short8 qf[2][4];
#pragma unroll
  for (int qt = 0; qt < 2; ++qt)
#pragma unroll
    for (int kkc = 0; kkc < 4; ++kkc)
      qf[qt][kkc] = *(const short8*)(Ip +
          ((size_t)b * P_TOT + qw + qt * 16 + l15) * NCO + kkc * 32 + g * 8);

  // ---- staging source pointers (pi-permuted rows, pre-XOR-swizzled cols)
  const char* srcK[4];
  const char* srcV[4];
  int ldsOff[4];
#pragma unroll
  for (int i = 0; i < 4; ++i) {
    int pos = (w * 4 + i) * 4 + (l >> 4);            // LDS K row (pi space)
    int nt = pos >> 4, gp = (pos >> 2) & 3, rr = pos & 3;
    int kp = (nt >> 1) * 32 + gp * 8 + (nt & 1) * 4 + rr;  // actual kp
    srcK[i] = (const char*)Lp +
              ((size_t)b * P_TOT + chunk * 2048 + kp) * 256 +
              (((l & 15) * 16) ^ ((pos & 7) << 4));
    int c = (w * 4 + i) * 8 + (l >> 3);              // LDS V row (c)
    srcV[i] = (const char*)Vg +
              ((size_t)(b * NCO + c) * P_TOT + chunk * 2048) * 2 +
              (((l & 7) * 16) ^ ((c & 7) << 4));
    ldsOff[i] = (w * 4 + i) * 1024;
  }

  float m_[2] = {-1e30f, -1e30f}, lsum[2] = {0.f, 0.f};
  f32x4 o[2][8];
#pragma unroll
  for (int qt = 0; qt < 2; ++qt)
#pragma unroll
    for (int ct = 0; ct < 8; ++ct) o[qt][ct] = (f32x4){0.f, 0.f, 0.f, 0.f};

  // prologue: stage tile 0 into buffer 0
#pragma unroll
  for (int i = 0; i < 4; ++i) {
    gload16(srcK[i], smem + ldsOff[i]);
    gload16(srcV[i], smem + 32768 + ldsOff[i]);
  }
  __syncthreads();

  int cur = 0;
  for (int kt = 0; kt < 32; ++kt) {
    if (kt + 1 < 32) {  // stage next tile into other buffer
#pragma unroll
      for (int i = 0; i < 4; ++i) {
        gload16(srcK[i] + (size_t)(kt + 1) * 16384,
                smem + (cur ^ 1) * 16384 + ldsOff[i]);
        gload16(srcV[i] + (size_t)(kt + 1) * 128,
                smem + 32768 + (cur ^ 1) * 16384 + ldsOff[i]);
      }
    }
    const char* Kb = smem + cur * 16384;
    const char* Vb = smem + 32768 + cur * 16384;

    // ---- S^T = K * Q^T  (pi-space rows)
    f32x4 s[2][4];
#pragma unroll
    for (int qt = 0; qt < 2; ++qt)
#pragma unroll
      for (int nt = 0; nt < 4; ++nt) s[qt][nt] = (f32x4){0.f, 0.f, 0.f, 0.f};
#pragma unroll
    for (int kkc = 0; kkc < 4; ++kkc) {
#pragma unroll
      for (int nt = 0; nt < 4; ++nt) {
        short8 kf = *(const short8*)(Kb + (nt * 16 + l15) * 256 +
                        ((kkc * 64 + g * 16) ^ ((l15 & 7) << 4)));
        s[0][nt] = __builtin_amdgcn_mfma_f32_16x16x32_bf16(kf, qf[0][kkc], s[0][nt], 0, 0, 0);
        s[1][nt] = __builtin_amdgcn_mfma_f32_16x16x32_bf16(kf, qf[1][kkc], s[1][nt], 0, 0, 0);
      }
    }

    // ---- online softmax: lane owns column q = l15 of S^T (16 vals/qt)
    unsigned pk[2][4][2];
    float f_[2];
#pragma unroll
    for (int qt = 0; qt < 2; ++qt) {
      float v0 = fmaxf(fmaxf(s[qt][0][0], s[qt][0][1]), fmaxf(s[qt][0][2], s[qt][0][3]));
      float v1 = fmaxf(fmaxf(s[qt][1][0], s[qt][1][1]), fmaxf(s[qt][1][2], s[qt][1][3]));
      float v2 = fmaxf(fmaxf(s[qt][2][0], s[qt][2][1]), fmaxf(s[qt][2][2], s[qt][2][3]));
      float v3 = fmaxf(fmaxf(s[qt][3][0], s[qt][3][1]), fmaxf(s[qt][3][2], s[qt][3][3]));
      float v = fmaxf(fmaxf(v0, v1), fmaxf(v2, v3));
      v = fmaxf(v, __shfl_xor(v, 16));
      v = fmaxf(v, __shfl_xor(v, 32));
      float mn = fmaxf(m_[qt], v * ALPHA);
      f_[qt] = __builtin_amdgcn_exp2f(m_[qt] - mn);
      m_[qt] = mn;
      float ps = 0.f;
#pragma unroll
      for (int nt = 0; nt < 4; ++nt) {
#pragma unroll
        for (int r = 0; r < 4; ++r) {
          float p = __builtin_amdgcn_exp2f(s[qt][nt][r] * ALPHA - mn);
          s[qt][nt][r] = p;
          ps += p;
        }
        pk[qt][nt][0] = cvtpk_bf16(s[qt][nt][0], s[qt][nt][1]);
        pk[qt][nt][1] = cvtpk_bf16(s[qt][nt][2], s[qt][nt][3]);
      }
      ps += __shfl_xor(ps, 16);
      ps += __shfl_xor(ps, 32);
      lsum[qt] = lsum[qt] * f_[qt] + ps;
    }

    // ---- rescale O (O rows live at q = 4g+r -> broadcast f from lane 4g+r)
#pragma unroll
    for (int qt = 0; qt < 2; ++qt)
#pragma unroll
      for (int r = 0; r < 4; ++r) {
        float fb = __shfl(f_[qt], 20 * g + r);
#pragma unroll
        for (int ct = 0; ct < 8; ++ct) o[qt][ct][r] *= fb;
      }

    // ---- O += P * V  (A-frag = pk in-lane thanks to pi permutation)
#pragma unroll
    for (int kk2 = 0; kk2 < 2; ++kk2) {
      short8 af[2];
#pragma unroll
      for (int qt = 0; qt < 2; ++qt) {
        union { unsigned u[4]; short8 v; } x;
        x.u[0] = pk[qt][2 * kk2][0];
        x.u[1] = pk[qt][2 * kk2][1];
        x.u[2] = pk[qt][2 * kk2 + 1][0];
        x.u[3] = pk[qt][2 * kk2 + 1][1];
        af[qt] = x.v;
      }
#pragma unroll
      for (int ct = 0; ct < 8; ++ct) {
        short8 vf = *(const short8*)(Vb + (ct * 16 + l15) * 128 +
                        ((kk2 * 64 + g * 16) ^ ((l15 & 7) << 4)));
        o[0][ct] = __builtin_amdgcn_mfma_f32_16x16x32_bf16(af[0], vf, o[0][ct], 0, 0, 0);
        o[1][ct] = __builtin_amdgcn_mfma_f32_16x16x32_bf16(af[1], vf, o[1][ct], 0, 0, 0);
      }
    }
    __syncthreads();
    cur ^= 1;
  }

  // ---- modality softmax
  float a0 = mw[0], a1 = mw[1];
  float mx = fmaxf(a0, a1);
  float e0 = __builtin_amdgcn_exp2f((a0 - mx) * 1.442695041f);
  float e1 = __builtin_amdgcn_exp2f((a1 - mx) * 1.442695041f);
  float w0 = e0 / (e0 + e1), w1 = e1 / (e0 + e1);

  float invb[2][4];
#pragma unroll
  for (int qt = 0; qt < 2; ++qt) {
    float inv = w1 / lsum[qt];
#pragma unroll
    for (int r = 0; r < 4; ++r) invb[qt][r] = __shfl(inv, 20 * g + r);
  }

  // ---- epilogue: blend + transpose through LDS, two c-halves
  float (*T)[132] = (float (*)[132])smem;
#pragma unroll
  for (int ch = 0; ch < 2; ++ch) {
    __syncthreads();
#pragma unroll
    for (int qt = 0; qt < 2; ++qt)
#pragma unroll
      for (int c4 = 0; c4 < 4; ++c4) {
        int ct = ch * 4 + c4;
#pragma unroll
        for (int r = 0; r < 4; ++r) {
          int qb = w * 32 + qt * 16 + 4 * g + r;
          float img = bf2f(Ip[((size_t)b * P_TOT + pq0 + qb) * NCO + ct * 16 + l15]);
          T[c4 * 16 + l15][qb] = w0 * img + invb[qt][r] * o[qt][ct][r];
        }
      }
    __syncthreads();
    {
      int c = t >> 2, q0 = (t & 3) * 32;
      float* Ob = out + ((size_t)b * NCO + ch * 64 + c) * P_TOT + pq0 + q0;
#pragma unroll
      for (int i2 = 0; i2 < 8; ++i2)
        *(f32x4*)(Ob + 4 * i2) = *(const f32x4*)&T[c][q0 + 4 * i2];
    }
  }
}

extern "C" void kernel_launch(void* const* d_in, const int* in_sizes, int n_in,
                              void* d_out, int out_size, void* d_ws, size_t ws_size,
                              hipStream_t stream) {
  const float* lidar = (const float*)d_in[0];
  const float* image = (const float*)d_in[1];
  const float* lw = (const float*)d_in[2];
  const float* lg = (const float*)d_in[3];
  const float* lb = (const float*)d_in[4];
  const float* lm = (const float*)d_in[5];
  const float* lv = (const float*)d_in[6];
  const float* iw = (const float*)d_in[7];
  const float* ig = (const float*)d_in[8];
  const float* ibt = (const float*)d_in[9];
  const float* im = (const float*)d_in[10];
  const float* iv = (const float*)d_in[11];
  const float* mw = (const float*)d_in[12];

  unsigned short* Lp = (unsigned short*)d_ws;            // [2][16384][128] bf16
  unsigned short* Ip = Lp + (size_t)2 * P_TOT * NCO;     // [2][16384][128] bf16
  unsigned short* Vg = Ip + (size_t)2 * P_TOT * NCO;     // [2][128][16384] bf16

  dim3 gp(P_TOT / 64, 2);
  proj_kernel<<<gp, 256, 0, stream>>>(lidar, lw, lg, lb, lm, lv, Lp, Vg, 256);
  proj_kernel<<<gp, 256, 0, stream>>>(image, iw, ig, ibt, im, iv, Ip, nullptr, 512);

  dim3 ga(2048 / 128, 8, 2);
  attn_kernel<<<ga, 256, 0, stream>>>(Lp, Ip, Vg, mw, (float*)d_out);
}

// Round 4
// 109.115 us; speedup vs baseline: 2.2660x; 1.8464x over previous
//
#include <hip/hip_runtime.h>
#include <hip/hip_bf16.h>

typedef __attribute__((ext_vector_type(4))) float f32x4;
typedef __attribute__((ext_vector_type(8))) short short8;

#define P_TOT 16384
#define NCO 128
#define EPS 1e-5f
// log2(e) / sqrt(128)
#define ALPHA 0.12752269f

__device__ __forceinline__ unsigned short f2bf(float f) {
  union { float f; unsigned u; } v; v.f = f;
  unsigned r = v.u + 0x7FFFu + ((v.u >> 16) & 1u);
  return (unsigned short)(r >> 16);
}
__device__ __forceinline__ float bf2f(unsigned short h) {
  union { unsigned u; float f; } v; v.u = ((unsigned)h) << 16;
  return v.f;
}
__device__ __forceinline__ unsigned cvtpk_bf16(float lo, float hi) {
  unsigned r;
  asm("v_cvt_pk_bf16_f32 %0, %1, %2" : "=v"(r) : "v"(lo), "v"(hi));
  return r;
}
__device__ __forceinline__ void gload16(const void* g, void* l) {
  __builtin_amdgcn_global_load_lds(
      (const __attribute__((address_space(1))) unsigned*)g,
      (__attribute__((address_space(3))) unsigned*)l, 16, 0, 0);
}

// ---------------------------------------------------------------------------
// MFMA 1x1 conv + BN(eval) + ReLU for BOTH modalities (zz&1 = batch,
// zz>>1 = modality). Block = 128p x 128co, BK = 64.
// X staged f32->bf16 into LDS [c][p] stride 264B (128 bf16 + 4 pad);
// A-frags via ds_read_u16 (2-way aliasing only = free);
// W staged bf16 [co][144B]; B-frags via b128. Outputs: [b][p][c] bf16 and,
// for lidar, [b][c][p] bf16 (Vg).
// ---------------------------------------------------------------------------
__global__ __launch_bounds__(256) void proj_mfma(
    const float* __restrict__ Xl, const float* __restrict__ Xi,
    const float* __restrict__ Wl, const float* __restrict__ Wi,
    const float* __restrict__ lgm, const float* __restrict__ lbt,
    const float* __restrict__ lmn, const float* __restrict__ lvr,
    const float* __restrict__ igm, const float* __restrict__ ibt,
    const float* __restrict__ imn, const float* __restrict__ ivr,
    unsigned short* __restrict__ Lp, unsigned short* __restrict__ Ip,
    unsigned short* __restrict__ Vg)
{
  // [0,16896): X bf16 [64][264B]; [16896,35328): W bf16 [128][144B]
  // epilogue union [0,34816): T bf16 [128][272B]
  // [35328,35840): sc f32[128]; [35840,36352): sh f32[128]
  __shared__ __align__(16) char smem[36352];
  float* sc_l = (float*)(smem + 35328);
  float* sh_l = (float*)(smem + 35840);

  const int t = threadIdx.x;
  const int w = t >> 6, l = t & 63, l15 = l & 15, g = l >> 4;
  const int zz = blockIdx.y, b = zz & 1, mod = zz >> 1;
  const int pb = blockIdx.x * 128;

  const float* Xg = mod ? Xi : Xl;
  const float* Wg = mod ? Wi : Wl;
  const int Cin = mod ? 512 : 256;
  unsigned short* outp = mod ? Ip : Lp;

  if (t < 128) {
    const float* G = mod ? igm : lgm;
    const float* Bt = mod ? ibt : lbt;
    const float* M = mod ? imn : lmn;
    const float* V = mod ? ivr : lvr;
    float s = G[t] / sqrtf(V[t] + EPS);
    sc_l[t] = s;
    sh_l[t] = Bt[t] - M[t] * s;
  }

  f32x4 o[2][8];
#pragma unroll
  for (int qt = 0; qt < 2; ++qt)
#pragma unroll
    for (int nt = 0; nt < 8; ++nt) o[qt][nt] = (f32x4){0.f, 0.f, 0.f, 0.f};

  uint2 xr[8], wr[8];
  auto load_tiles = [&](int s) {
    int cc = s * 64;
#pragma unroll
    for (int i = 0; i < 8; ++i) {
      int e = t + 256 * i;
      int c = e >> 5, p4 = e & 31;
      f32x4 x = *(const f32x4*)(Xg + ((size_t)(b * Cin + cc + c)) * P_TOT + pb + p4 * 4);
      xr[i].x = cvtpk_bf16(x[0], x[1]);
      xr[i].y = cvtpk_bf16(x[2], x[3]);
    }
#pragma unroll
    for (int i = 0; i < 8; ++i) {
      int e = t + 256 * i;
      int co = e >> 4, c4 = e & 15;
      f32x4 wv = *(const f32x4*)(Wg + (size_t)co * Cin + cc + c4 * 4);
      wr[i].x = cvtpk_bf16(wv[0], wv[1]);
      wr[i].y = cvtpk_bf16(wv[2], wv[3]);
    }
  };

  load_tiles(0);
  const int nsteps = Cin >> 6;
  for (int s = 0; s < nsteps; ++s) {
    __syncthreads();  // previous compute done; LDS free
#pragma unroll
    for (int i = 0; i < 8; ++i) {
      int e = t + 256 * i;
      int c = e >> 5, p4 = e & 31;
      *(uint2*)(smem + c * 264 + p4 * 8) = xr[i];
    }
#pragma unroll
    for (int i = 0; i < 8; ++i) {
      int e = t + 256 * i;
      int co = e >> 4, c4 = e & 15;
      *(uint2*)(smem + 16896 + co * 144 + c4 * 8) = wr[i];
    }
    if (s + 1 < nsteps) load_tiles(s + 1);  // hide HBM under compute
    __syncthreads();

#pragma unroll
    for (int kkc = 0; kkc < 2; ++kkc) {
      short8 a[2];
#pragma unroll
      for (int qt = 0; qt < 2; ++qt) {
        const char* ab = smem + (kkc * 32 + g * 8) * 264 + (w * 32 + qt * 16 + l15) * 2;
        union { unsigned uu[4]; short8 v; } cv;
#pragma unroll
        for (int e2 = 0; e2 < 4; ++e2) {
          unsigned lo = *(const unsigned short*)(ab + (2 * e2) * 264);
          unsigned hi = *(const unsigned short*)(ab + (2 * e2 + 1) * 264);
          cv.uu[e2] = lo | (hi << 16);
        }
        a[qt] = cv.v;
      }
#pragma unroll
      for (int nt = 0; nt < 8; ++nt) {
        short8 wf = *(const short8*)(smem + 16896 + (nt * 16 + l15) * 144 + kkc * 64 + g * 16);
        o[0][nt] = __builtin_amdgcn_mfma_f32_16x16x32_bf16(a[0], wf, o[0][nt], 0, 0, 0);
        o[1][nt] = __builtin_amdgcn_mfma_f32_16x16x32_bf16(a[1], wf, o[1][nt], 0, 0, 0);
      }
    }
  }

  // ---- epilogue: BN + ReLU -> bf16 T[p][co], then vectorized global writes
  __syncthreads();
#pragma unroll
  for (int nt = 0; nt < 8; ++nt) {
    float scv = sc_l[nt * 16 + l15];
    float shv = sh_l[nt * 16 + l15];
#pragma unroll
    for (int qt = 0; qt < 2; ++qt)
#pragma unroll
      for (int r = 0; r < 4; ++r) {
        int p = w * 32 + qt * 16 + 4 * g + r;
        float y = fmaxf(fmaf(o[qt][nt][r], scv, shv), 0.f);
        *(unsigned short*)(smem + p * 272 + (nt * 16 + l15) * 2) = f2bf(y);
      }
  }
  __syncthreads();
  {
    int p = t >> 1, half = t & 1;
    const char* Tb = smem + p * 272 + half * 128;
    unsigned short* ob = outp + ((size_t)b * P_TOT + pb + p) * NCO + half * 64;
#pragma unroll
    for (int i = 0; i < 8; ++i)
      *(uint4*)(ob + i * 8) = *(const uint4*)(Tb + i * 16);
  }
  if (mod == 0) {  // Vg [b][c][p] for attention V staging
    int co = t & 127, ph = t >> 7;
    unsigned short* vb = Vg + ((size_t)b * NCO + co) * P_TOT + pb + ph * 64;
    unsigned pkv[32];
#pragma unroll
    for (int j2 = 0; j2 < 32; ++j2) {
      unsigned lo = *(const unsigned short*)(smem + (ph * 64 + 2 * j2) * 272 + co * 2);
      unsigned hi = *(const unsigned short*)(smem + (ph * 64 + 2 * j2 + 1) * 272 + co * 2);
      pkv[j2] = lo | (hi << 16);
    }
#pragma unroll
    for (int i = 0; i < 8; ++i)
      *(uint4*)(vb + i * 8) = *(const uint4*)&pkv[i * 4];
  }
}

// ---------------------------------------------------------------------------
// Block-diagonal flash attention (q=image_proj, k=v=lidar_proj) + blend.
// (unchanged from round 2 — verified passing)
// ---------------------------------------------------------------------------
__global__ __launch_bounds__(256) void attn_kernel(
    const unsigned short* __restrict__ Lp,  // [B][P][128] bf16 (K rows)
    const unsigned short* __restrict__ Ip,  // [B][P][128] bf16 (Q rows)
    const unsigned short* __restrict__ Vg,  // [B][128][P] bf16 (V cols)
    const float* __restrict__ mw,           // [2]
    float* __restrict__ out)                // [B][128][P] f32
{
  __shared__ __align__(16) char smem[65536];

  const int t = threadIdx.x;
  const int w = t >> 6, l = t & 63;
  const int l15 = l & 15, g = l >> 4;
  const int b = blockIdx.z, chunk = blockIdx.y;
  const int pq0 = chunk * 2048 + blockIdx.x * 128;
  const int qw = pq0 + w * 32;

  short8 qf[2][4];
#pragma unroll
  for (int qt = 0; qt < 2; ++qt)
#pragma unroll
    for (int kkc = 0; kkc < 4; ++kkc)
      qf[qt][kkc] = *(const short8*)(Ip +
          ((size_t)b * P_TOT + qw + qt * 16 + l15) * NCO + kkc * 32 + g * 8);

  const char* srcK[4];
  const char* srcV[4];
  int ldsOff[4];
#pragma unroll
  for (int i = 0; i < 4; ++i) {
    int pos = (w * 4 + i) * 4 + (l >> 4);
    int nt = pos >> 4, gp = (pos >> 2) & 3, rr = pos & 3;
    int kp = (nt >> 1) * 32 + gp * 8 + (nt & 1) * 4 + rr;
    srcK[i] = (const char*)Lp +
              ((size_t)b * P_TOT + chunk * 2048 + kp) * 256 +
              (((l & 15) * 16) ^ ((pos & 7) << 4));
    int c = (w * 4 + i) * 8 + (l >> 3);
    srcV[i] = (const char*)Vg +
              ((size_t)(b * NCO + c) * P_TOT + chunk * 2048) * 2 +
              (((l & 7) * 16) ^ ((c & 7) << 4));
    ldsOff[i] = (w * 4 + i) * 1024;
  }

  float m_[2] = {-1e30f, -1e30f}, lsum[2] = {0.f, 0.f};
  f32x4 o[2][8];
#pragma unroll
  for (int qt = 0; qt < 2; ++qt)
#pragma unroll
    for (int ct = 0; ct < 8; ++ct) o[qt][ct] = (f32x4){0.f, 0.f, 0.f, 0.f};

#pragma unroll
  for (int i = 0; i < 4; ++i) {
    gload16(srcK[i], smem + ldsOff[i]);
    gload16(srcV[i], smem + 32768 + ldsOff[i]);
  }
  __syncthreads();

  int cur = 0;
  for (int kt = 0; kt < 32; ++kt) {
    if (kt + 1 < 32) {
#pragma unroll
      for (int i = 0; i < 4; ++i) {
        gload16(srcK[i] + (size_t)(kt + 1) * 16384,
                smem + (cur ^ 1) * 16384 + ldsOff[i]);
        gload16(srcV[i] + (size_t)(kt + 1) * 128,
                smem + 32768 + (cur ^ 1) * 16384 + ldsOff[i]);
      }
    }
    const char* Kb = smem + cur * 16384;
    const char* Vb = smem + 32768 + cur * 16384;

    f32x4 s[2][4];
#pragma unroll
    for (int qt = 0; qt < 2; ++qt)
#pragma unroll
      for (int nt = 0; nt < 4; ++nt) s[qt][nt] = (f32x4){0.f, 0.f, 0.f, 0.f};
#pragma unroll
    for (int kkc = 0; kkc < 4; ++kkc) {
#pragma unroll
      for (int nt = 0; nt < 4; ++nt) {
        short8 kf = *(const short8*)(Kb + (nt * 16 + l15) * 256 +
                        ((kkc * 64 + g * 16) ^ ((l15 & 7) << 4)));
        s[0][nt] = __builtin_amdgcn_mfma_f32_16x16x32_bf16(kf, qf[0][kkc], s[0][nt], 0, 0, 0);
        s[1][nt] = __builtin_amdgcn_mfma_f32_16x16x32_bf16(kf, qf[1][kkc], s[1][nt], 0, 0, 0);
      }
    }

    unsigned pk[2][4][2];
    float f_[2];
#pragma unroll
    for (int qt = 0; qt < 2; ++qt) {
      float v0 = fmaxf(fmaxf(s[qt][0][0], s[qt][0][1]), fmaxf(s[qt][0][2], s[qt][0][3]));
      float v1 = fmaxf(fmaxf(s[qt][1][0], s[qt][1][1]), fmaxf(s[qt][1][2], s[qt][1][3]));
      float v2 = fmaxf(fmaxf(s[qt][2][0], s[qt][2][1]), fmaxf(s[qt][2][2], s[qt][2][3]));
      float v3 = fmaxf(fmaxf(s[qt][3][0], s[qt][3][1]), fmaxf(s[qt][3][2], s[qt][3][3]));
      float v = fmaxf(fmaxf(v0, v1), fmaxf(v2, v3));
      v = fmaxf(v, __shfl_xor(v, 16));
      v = fmaxf(v, __shfl_xor(v, 32));
      float mn = fmaxf(m_[qt], v * ALPHA);
      f_[qt] = __builtin_amdgcn_exp2f(m_[qt] - mn);
      m_[qt] = mn;
      float ps = 0.f;
#pragma unroll
      for (int nt = 0; nt < 4; ++nt) {
#pragma unroll
        for (int r = 0; r < 4; ++r) {
          float p = __builtin_amdgcn_exp2f(s[qt][nt][r] * ALPHA - mn);
          s[qt][nt][r] = p;
          ps += p;
        }
        pk[qt][nt][0] = cvtpk_bf16(s[qt][nt][0], s[qt][nt][1]);
        pk[qt][nt][1] = cvtpk_bf16(s[qt][nt][2], s[qt][nt][3]);
      }
      ps += __shfl_xor(ps, 16);
      ps += __shfl_xor(ps, 32);
      lsum[qt] = lsum[qt] * f_[qt] + ps;
    }

#pragma unroll
    for (int qt = 0; qt < 2; ++qt)
#pragma unroll
      for (int r = 0; r < 4; ++r) {
        float fb = __shfl(f_[qt], 20 * g + r);
#pragma unroll
        for (int ct = 0; ct < 8; ++ct) o[qt][ct][r] *= fb;
      }

#pragma unroll
    for (int kk2 = 0; kk2 < 2; ++kk2) {
      short8 af[2];
#pragma unroll
      for (int qt = 0; qt < 2; ++qt) {
        union { unsigned u[4]; short8 v; } x;
        x.u[0] = pk[qt][2 * kk2][0];
        x.u[1] = pk[qt][2 * kk2][1];
        x.u[2] = pk[qt][2 * kk2 + 1][0];
        x.u[3] = pk[qt][2 * kk2 + 1][1];
        af[qt] = x.v;
      }
#pragma unroll
      for (int ct = 0; ct < 8; ++ct) {
        short8 vf = *(const short8*)(Vb + (ct * 16 + l15) * 128 +
                        ((kk2 * 64 + g * 16) ^ ((l15 & 7) << 4)));
        o[0][ct] = __builtin_amdgcn_mfma_f32_16x16x32_bf16(af[0], vf, o[0][ct], 0, 0, 0);
        o[1][ct] = __builtin_amdgcn_mfma_f32_16x16x32_bf16(af[1], vf, o[1][ct], 0, 0, 0);
      }
    }
    __syncthreads();
    cur ^= 1;
  }

  float a0 = mw[0], a1 = mw[1];
  float mx = fmaxf(a0, a1);
  float e0 = __builtin_amdgcn_exp2f((a0 - mx) * 1.442695041f);
  float e1 = __builtin_amdgcn_exp2f((a1 - mx) * 1.442695041f);
  float w0 = e0 / (e0 + e1), w1 = e1 / (e0 + e1);

  float invb[2][4];
#pragma unroll
  for (int qt = 0; qt < 2; ++qt) {
    float inv = w1 / lsum[qt];
#pragma unroll
    for (int r = 0; r < 4; ++r) invb[qt][r] = __shfl(inv, 20 * g + r);
  }

  float (*T)[132] = (float (*)[132])smem;
#pragma unroll
  for (int ch = 0; ch < 2; ++ch) {
    __syncthreads();
#pragma unroll
    for (int qt = 0; qt < 2; ++qt)
#pragma unroll
      for (int c4 = 0; c4 < 4; ++c4) {
        int ct = ch * 4 + c4;
#pragma unroll
        for (int r = 0; r < 4; ++r) {
          int qb = w * 32 + qt * 16 + 4 * g + r;
          float img = bf2f(Ip[((size_t)b * P_TOT + pq0 + qb) * NCO + ct * 16 + l15]);
          T[c4 * 16 + l15][qb] = w0 * img + invb[qt][r] * o[qt][ct][r];
        }
      }
    __syncthreads();
    {
      int c = t >> 2, q0 = (t & 3) * 32;
      float* Ob = out + ((size_t)b * NCO + ch * 64 + c) * P_TOT + pq0 + q0;
#pragma unroll
      for (int i2 = 0; i2 < 8; ++i2)
        *(f32x4*)(Ob + 4 * i2) = *(const f32x4*)&T[c][q0 + 4 * i2];
    }
  }
}

extern "C" void kernel_launch(void* const* d_in, const int* in_sizes, int n_in,
                              void* d_out, int out_size, void* d_ws, size_t ws_size,
                              hipStream_t stream) {
  const float* lidar = (const float*)d_in[0];
  const float* image = (const float*)d_in[1];
  const float* lw = (const float*)d_in[2];
  const float* lg = (const float*)d_in[3];
  const float* lb = (const float*)d_in[4];
  const float* lm = (const float*)d_in[5];
  const float* lv = (const float*)d_in[6];
  const float* iw = (const float*)d_in[7];
  const float* ig = (const float*)d_in[8];
  const float* ibt = (const float*)d_in[9];
  const float* im = (const float*)d_in[10];
  const float* iv = (const float*)d_in[11];
  const float* mw = (const float*)d_in[12];

  unsigned short* Lp = (unsigned short*)d_ws;            // [2][16384][128] bf16
  unsigned short* Ip = Lp + (size_t)2 * P_TOT * NCO;     // [2][16384][128] bf16
  unsigned short* Vg = Ip + (size_t)2 * P_TOT * NCO;     // [2][128][16384] bf16

  dim3 gp(P_TOT / 128, 4);
  proj_mfma<<<gp, 256, 0, stream>>>(lidar, image, lw, iw,
                                    lg, lb, lm, lv, ig, ibt, im, iv,
                                    Lp, Ip, Vg);

  dim3 ga(2048 / 128, 8, 2);
  attn_kernel<<<ga, 256, 0, stream>>>(Lp, Ip, Vg, mw, (float*)d_out);
}

// Round 5
// 97.630 us; speedup vs baseline: 2.5326x; 1.1176x over previous
//
#include <hip/hip_runtime.h>
#include <hip/hip_bf16.h>

typedef __attribute__((ext_vector_type(4))) float f32x4;
typedef __attribute__((ext_vector_type(8))) short short8;

#define P_TOT 16384
#define NCO 128
#define EPS 1e-5f
// log2(e) / sqrt(128)
#define ALPHA 0.12752269f

__device__ __forceinline__ unsigned short f2bf(float f) {
  union { float f; unsigned u; } v; v.f = f;
  unsigned r = v.u + 0x7FFFu + ((v.u >> 16) & 1u);
  return (unsigned short)(r >> 16);
}
__device__ __forceinline__ float bf2f(unsigned short h) {
  union { unsigned u; float f; } v; v.u = ((unsigned)h) << 16;
  return v.f;
}
__device__ __forceinline__ unsigned cvtpk_bf16(float lo, float hi) {
  unsigned r;
  asm("v_cvt_pk_bf16_f32 %0, %1, %2" : "=v"(r) : "v"(lo), "v"(hi));
  return r;
}
__device__ __forceinline__ void gload16(const void* g, void* l) {
  __builtin_amdgcn_global_load_lds(
      (const __attribute__((address_space(1))) unsigned*)g,
      (__attribute__((address_space(3))) unsigned*)l, 16, 0, 0);
}

// ---------------------------------------------------------------------------
// MFMA 1x1 conv + BN(eval) + ReLU for BOTH modalities (zz&1 = batch,
// zz>>1 = modality). Block = 128p x 128co, BK = 64.
// (byte-identical to round 4 — verified passing)
// ---------------------------------------------------------------------------
__global__ __launch_bounds__(256) void proj_mfma(
    const float* __restrict__ Xl, const float* __restrict__ Xi,
    const float* __restrict__ Wl, const float* __restrict__ Wi,
    const float* __restrict__ lgm, const float* __restrict__ lbt,
    const float* __restrict__ lmn, const float* __restrict__ lvr,
    const float* __restrict__ igm, const float* __restrict__ ibt,
    const float* __restrict__ imn, const float* __restrict__ ivr,
    unsigned short* __restrict__ Lp, unsigned short* __restrict__ Ip,
    unsigned short* __restrict__ Vg)
{
  __shared__ __align__(16) char smem[36352];
  float* sc_l = (float*)(smem + 35328);
  float* sh_l = (float*)(smem + 35840);

  const int t = threadIdx.x;
  const int w = t >> 6, l = t & 63, l15 = l & 15, g = l >> 4;
  const int zz = blockIdx.y, b = zz & 1, mod = zz >> 1;
  const int pb = blockIdx.x * 128;

  const float* Xg = mod ? Xi : Xl;
  const float* Wg = mod ? Wi : Wl;
  const int Cin = mod ? 512 : 256;
  unsigned short* outp = mod ? Ip : Lp;

  if (t < 128) {
    const float* G = mod ? igm : lgm;
    const float* Bt = mod ? ibt : lbt;
    const float* M = mod ? imn : lmn;
    const float* V = mod ? ivr : lvr;
    float s = G[t] / sqrtf(V[t] + EPS);
    sc_l[t] = s;
    sh_l[t] = Bt[t] - M[t] * s;
  }

  f32x4 o[2][8];
#pragma unroll
  for (int qt = 0; qt < 2; ++qt)
#pragma unroll
    for (int nt = 0; nt < 8; ++nt) o[qt][nt] = (f32x4){0.f, 0.f, 0.f, 0.f};

  uint2 xr[8], wr[8];
  auto load_tiles = [&](int s) {
    int cc = s * 64;
#pragma unroll
    for (int i = 0; i < 8; ++i) {
      int e = t + 256 * i;
      int c = e >> 5, p4 = e & 31;
      f32x4 x = *(const f32x4*)(Xg + ((size_t)(b * Cin + cc + c)) * P_TOT + pb + p4 * 4);
      xr[i].x = cvtpk_bf16(x[0], x[1]);
      xr[i].y = cvtpk_bf16(x[2], x[3]);
    }
#pragma unroll
    for (int i = 0; i < 8; ++i) {
      int e = t + 256 * i;
      int co = e >> 4, c4 = e & 15;
      f32x4 wv = *(const f32x4*)(Wg + (size_t)co * Cin + cc + c4 * 4);
      wr[i].x = cvtpk_bf16(wv[0], wv[1]);
      wr[i].y = cvtpk_bf16(wv[2], wv[3]);
    }
  };

  load_tiles(0);
  const int nsteps = Cin >> 6;
  for (int s = 0; s < nsteps; ++s) {
    __syncthreads();
#pragma unroll
    for (int i = 0; i < 8; ++i) {
      int e = t + 256 * i;
      int c = e >> 5, p4 = e & 31;
      *(uint2*)(smem + c * 264 + p4 * 8) = xr[i];
    }
#pragma unroll
    for (int i = 0; i < 8; ++i) {
      int e = t + 256 * i;
      int co = e >> 4, c4 = e & 15;
      *(uint2*)(smem + 16896 + co * 144 + c4 * 8) = wr[i];
    }
    if (s + 1 < nsteps) load_tiles(s + 1);
    __syncthreads();

#pragma unroll
    for (int kkc = 0; kkc < 2; ++kkc) {
      short8 a[2];
#pragma unroll
      for (int qt = 0; qt < 2; ++qt) {
        const char* ab = smem + (kkc * 32 + g * 8) * 264 + (w * 32 + qt * 16 + l15) * 2;
        union { unsigned uu[4]; short8 v; } cv;
#pragma unroll
        for (int e2 = 0; e2 < 4; ++e2) {
          unsigned lo = *(const unsigned short*)(ab + (2 * e2) * 264);
          unsigned hi = *(const unsigned short*)(ab + (2 * e2 + 1) * 264);
          cv.uu[e2] = lo | (hi << 16);
        }
        a[qt] = cv.v;
      }
#pragma unroll
      for (int nt = 0; nt < 8; ++nt) {
        short8 wf = *(const short8*)(smem + 16896 + (nt * 16 + l15) * 144 + kkc * 64 + g * 16);
        o[0][nt] = __builtin_amdgcn_mfma_f32_16x16x32_bf16(a[0], wf, o[0][nt], 0, 0, 0);
        o[1][nt] = __builtin_amdgcn_mfma_f32_16x16x32_bf16(a[1], wf, o[1][nt], 0, 0, 0);
      }
    }
  }

  __syncthreads();
#pragma unroll
  for (int nt = 0; nt < 8; ++nt) {
    float scv = sc_l[nt * 16 + l15];
    float shv = sh_l[nt * 16 + l15];
#pragma unroll
    for (int qt = 0; qt < 2; ++qt)
#pragma unroll
      for (int r = 0; r < 4; ++r) {
        int p = w * 32 + qt * 16 + 4 * g + r;
        float y = fmaxf(fmaf(o[qt][nt][r], scv, shv), 0.f);
        *(unsigned short*)(smem + p * 272 + (nt * 16 + l15) * 2) = f2bf(y);
      }
  }
  __syncthreads();
  {
    int p = t >> 1, half = t & 1;
    const char* Tb = smem + p * 272 + half * 128;
    unsigned short* ob = outp + ((size_t)b * P_TOT + pb + p) * NCO + half * 64;
#pragma unroll
    for (int i = 0; i < 8; ++i)
      *(uint4*)(ob + i * 8) = *(const uint4*)(Tb + i * 16);
  }
  if (mod == 0) {
    int co = t & 127, ph = t >> 7;
    unsigned short* vb = Vg + ((size_t)b * NCO + co) * P_TOT + pb + ph * 64;
    unsigned pkv[32];
#pragma unroll
    for (int j2 = 0; j2 < 32; ++j2) {
      unsigned lo = *(const unsigned short*)(smem + (ph * 64 + 2 * j2) * 272 + co * 2);
      unsigned hi = *(const unsigned short*)(smem + (ph * 64 + 2 * j2 + 1) * 272 + co * 2);
      pkv[j2] = lo | (hi << 16);
    }
#pragma unroll
    for (int i = 0; i < 8; ++i)
      *(uint4*)(vb + i * 8) = *(const uint4*)&pkv[i * 4];
  }
}

// ---------------------------------------------------------------------------
// Block-diagonal flash attention + blend. Same math as round 4; changes:
// (1) XCD-aware 1D grid: gid%8 == chunk, so all 32 blocks of a chunk share
//     one XCD's L2 (K/V working set 2MB < 4MB L2) -> gload_lds drains at L2
//     latency instead of HBM.
// (2) T13 defer-rescale: skip f/rescale when tile max doesn't exceed m+8
//     (exp2 domain; P bounded by 2^8, safe in f32/bf16).
// ---------------------------------------------------------------------------
__global__ __launch_bounds__(256) void attn_kernel(
    const unsigned short* __restrict__ Lp,  // [B][P][128] bf16 (K rows)
    const unsigned short* __restrict__ Ip,  // [B][P][128] bf16 (Q rows)
    const unsigned short* __restrict__ Vg,  // [B][128][P] bf16 (V cols)
    const float* __restrict__ mw,           // [2]
    float* __restrict__ out)                // [B][128][P] f32
{
  __shared__ __align__(16) char smem[65536];

  const int t = threadIdx.x;
  const int w = t >> 6, l = t & 63;
  const int l15 = l & 15, g = l >> 4;
  // XCD swizzle: gid = bx*16 + b*8 + chunk  ->  gid % 8 == chunk
  const int gid = blockIdx.x;
  const int bx = gid >> 4;
  const int chunk = gid & 7;
  const int b = (gid >> 3) & 1;
  const int pq0 = chunk * 2048 + bx * 128;
  const int qw = pq0 + w * 32;

  short8 qf[2][4];
#pragma unroll
  for (int qt = 0; qt < 2; ++qt)
#pragma unroll
    for (int kkc = 0; kkc < 4; ++kkc)
      qf[qt][kkc] = *(const short8*)(Ip +
          ((size_t)b * P_TOT + qw + qt * 16 + l15) * NCO + kkc * 32 + g * 8);

  const char* srcK[4];
  const char* srcV[4];
  int ldsOff[4];
#pragma unroll
  for (int i = 0; i < 4; ++i) {
    int pos = (w * 4 + i) * 4 + (l >> 4);
    int nt = pos >> 4, gp = (pos >> 2) & 3, rr = pos & 3;
    int kp = (nt >> 1) * 32 + gp * 8 + (nt & 1) * 4 + rr;
    srcK[i] = (const char*)Lp +
              ((size_t)b * P_TOT + chunk * 2048 + kp) * 256 +
              (((l & 15) * 16) ^ ((pos & 7) << 4));
    int c = (w * 4 + i) * 8 + (l >> 3);
    srcV[i] = (const char*)Vg +
              ((size_t)(b * NCO + c) * P_TOT + chunk * 2048) * 2 +
              (((l & 7) * 16) ^ ((c & 7) << 4));
    ldsOff[i] = (w * 4 + i) * 1024;
  }

  float m_[2] = {-1e30f, -1e30f}, lsum[2] = {0.f, 0.f};
  f32x4 o[2][8];
#pragma unroll
  for (int qt = 0; qt < 2; ++qt)
#pragma unroll
    for (int ct = 0; ct < 8; ++ct) o[qt][ct] = (f32x4){0.f, 0.f, 0.f, 0.f};

#pragma unroll
  for (int i = 0; i < 4; ++i) {
    gload16(srcK[i], smem + ldsOff[i]);
    gload16(srcV[i], smem + 32768 + ldsOff[i]);
  }
  __syncthreads();

  int cur = 0;
  for (int kt = 0; kt < 32; ++kt) {
    if (kt + 1 < 32) {
#pragma unroll
      for (int i = 0; i < 4; ++i) {
        gload16(srcK[i] + (size_t)(kt + 1) * 16384,
                smem + (cur ^ 1) * 16384 + ldsOff[i]);
        gload16(srcV[i] + (size_t)(kt + 1) * 128,
                smem + 32768 + (cur ^ 1) * 16384 + ldsOff[i]);
      }
    }
    const char* Kb = smem + cur * 16384;
    const char* Vb = smem + 32768 + cur * 16384;

    f32x4 s[2][4];
#pragma unroll
    for (int qt = 0; qt < 2; ++qt)
#pragma unroll
      for (int nt = 0; nt < 4; ++nt) s[qt][nt] = (f32x4){0.f, 0.f, 0.f, 0.f};
#pragma unroll
    for (int kkc = 0; kkc < 4; ++kkc) {
#pragma unroll
      for (int nt = 0; nt < 4; ++nt) {
        short8 kf = *(const short8*)(Kb + (nt * 16 + l15) * 256 +
                        ((kkc * 64 + g * 16) ^ ((l15 & 7) << 4)));
        s[0][nt] = __builtin_amdgcn_mfma_f32_16x16x32_bf16(kf, qf[0][kkc], s[0][nt], 0, 0, 0);
        s[1][nt] = __builtin_amdgcn_mfma_f32_16x16x32_bf16(kf, qf[1][kkc], s[1][nt], 0, 0, 0);
      }
    }

    unsigned pk[2][4][2];
    float f_[2];
    int upd[2];
#pragma unroll
    for (int qt = 0; qt < 2; ++qt) {
      float v0 = fmaxf(fmaxf(s[qt][0][0], s[qt][0][1]), fmaxf(s[qt][0][2], s[qt][0][3]));
      float v1 = fmaxf(fmaxf(s[qt][1][0], s[qt][1][1]), fmaxf(s[qt][1][2], s[qt][1][3]));
      float v2 = fmaxf(fmaxf(s[qt][2][0], s[qt][2][1]), fmaxf(s[qt][2][2], s[qt][2][3]));
      float v3 = fmaxf(fmaxf(s[qt][3][0], s[qt][3][1]), fmaxf(s[qt][3][2], s[qt][3][3]));
      float v = fmaxf(fmaxf(v0, v1), fmaxf(v2, v3));
      v = fmaxf(v, __shfl_xor(v, 16));
      v = fmaxf(v, __shfl_xor(v, 32));
      float pm = v * ALPHA;
      upd[qt] = __any(pm > m_[qt] + 8.f);  // T13 defer-rescale (THR=8, exp2 dom)
      float mn = m_[qt];
      if (upd[qt]) {
        mn = fmaxf(m_[qt], pm);
        f_[qt] = __builtin_amdgcn_exp2f(m_[qt] - mn);
        m_[qt] = mn;
      } else {
        f_[qt] = 1.f;
      }
      float ps = 0.f;
#pragma unroll
      for (int nt = 0; nt < 4; ++nt) {
#pragma unroll
        for (int r = 0; r < 4; ++r) {
          float p = __builtin_amdgcn_exp2f(s[qt][nt][r] * ALPHA - mn);
          s[qt][nt][r] = p;
          ps += p;
        }
        pk[qt][nt][0] = cvtpk_bf16(s[qt][nt][0], s[qt][nt][1]);
        pk[qt][nt][1] = cvtpk_bf16(s[qt][nt][2], s[qt][nt][3]);
      }
      ps += __shfl_xor(ps, 16);
      ps += __shfl_xor(ps, 32);
      lsum[qt] = lsum[qt] * f_[qt] + ps;
    }

#pragma unroll
    for (int qt = 0; qt < 2; ++qt)
      if (upd[qt]) {
#pragma unroll
        for (int r = 0; r < 4; ++r) {
          float fb = __shfl(f_[qt], 20 * g + r);
#pragma unroll
          for (int ct = 0; ct < 8; ++ct) o[qt][ct][r] *= fb;
        }
      }

#pragma unroll
    for (int kk2 = 0; kk2 < 2; ++kk2) {
      short8 af[2];
#pragma unroll
      for (int qt = 0; qt < 2; ++qt) {
        union { unsigned u[4]; short8 v; } x;
        x.u[0] = pk[qt][2 * kk2][0];
        x.u[1] = pk[qt][2 * kk2][1];
        x.u[2] = pk[qt][2 * kk2 + 1][0];
        x.u[3] = pk[qt][2 * kk2 + 1][1];
        af[qt] = x.v;
      }
#pragma unroll
      for (int ct = 0; ct < 8; ++ct) {
        short8 vf = *(const short8*)(Vb + (ct * 16 + l15) * 128 +
                        ((kk2 * 64 + g * 16) ^ ((l15 & 7) << 4)));
        o[0][ct] = __builtin_amdgcn_mfma_f32_16x16x32_bf16(af[0], vf, o[0][ct], 0, 0, 0);
        o[1][ct] = __builtin_amdgcn_mfma_f32_16x16x32_bf16(af[1], vf, o[1][ct], 0, 0, 0);
      }
    }
    __syncthreads();
    cur ^= 1;
  }

  float a0 = mw[0], a1 = mw[1];
  float mx = fmaxf(a0, a1);
  float e0 = __builtin_amdgcn_exp2f((a0 - mx) * 1.442695041f);
  float e1 = __builtin_amdgcn_exp2f((a1 - mx) * 1.442695041f);
  float w0 = e0 / (e0 + e1), w1 = e1 / (e0 + e1);

  float invb[2][4];
#pragma unroll
  for (int qt = 0; qt < 2; ++qt) {
    float inv = w1 / lsum[qt];
#pragma unroll
    for (int r = 0; r < 4; ++r) invb[qt][r] = __shfl(inv, 20 * g + r);
  }

  float (*T)[132] = (float (*)[132])smem;
#pragma unroll
  for (int ch = 0; ch < 2; ++ch) {
    __syncthreads();
#pragma unroll
    for (int qt = 0; qt < 2; ++qt)
#pragma unroll
      for (int c4 = 0; c4 < 4; ++c4) {
        int ct = ch * 4 + c4;
#pragma unroll
        for (int r = 0; r < 4; ++r) {
          int qb = w * 32 + qt * 16 + 4 * g + r;
          float img = bf2f(Ip[((size_t)b * P_TOT + pq0 + qb) * NCO + ct * 16 + l15]);
          T[c4 * 16 + l15][qb] = w0 * img + invb[qt][r] * o[qt][ct][r];
        }
      }
    __syncthreads();
    {
      int c = t >> 2, q0 = (t & 3) * 32;
      float* Ob = out + ((size_t)b * NCO + ch * 64 + c) * P_TOT + pq0 + q0;
#pragma unroll
      for (int i2 = 0; i2 < 8; ++i2)
        *(f32x4*)(Ob + 4 * i2) = *(const f32x4*)&T[c][q0 + 4 * i2];
    }
  }
}

extern "C" void kernel_launch(void* const* d_in, const int* in_sizes, int n_in,
                              void* d_out, int out_size, void* d_ws, size_t ws_size,
                              hipStream_t stream) {
  const float* lidar = (const float*)d_in[0];
  const float* image = (const float*)d_in[1];
  const float* lw = (const float*)d_in[2];
  const float* lg = (const float*)d_in[3];
  const float* lb = (const float*)d_in[4];
  const float* lm = (const float*)d_in[5];
  const float* lv = (const float*)d_in[6];
  const float* iw = (const float*)d_in[7];
  const float* ig = (const float*)d_in[8];
  const float* ibt = (const float*)d_in[9];
  const float* im = (const float*)d_in[10];
  const float* iv = (const float*)d_in[11];
  const float* mw = (const float*)d_in[12];

  unsigned short* Lp = (unsigned short*)d_ws;            // [2][16384][128] bf16
  unsigned short* Ip = Lp + (size_t)2 * P_TOT * NCO;     // [2][16384][128] bf16
  unsigned short* Vg = Ip + (size_t)2 * P_TOT * NCO;     // [2][128][16384] bf16

  dim3 gp(P_TOT / 128, 4);
  proj_mfma<<<gp, 256, 0, stream>>>(lidar, image, lw, iw,
                                    lg, lb, lm, lv, ig, ibt, im, iv,
                                    Lp, Ip, Vg);

  attn_kernel<<<dim3(256), 256, 0, stream>>>(Lp, Ip, Vg, mw, (float*)d_out);
}

// Round 6
// 81.334 us; speedup vs baseline: 3.0400x; 1.2004x over previous
//
#include <hip/hip_runtime.h>
#include <hip/hip_bf16.h>

typedef __attribute__((ext_vector_type(4))) float f32x4;
typedef __attribute__((ext_vector_type(8))) short short8;

#define P_TOT 16384
#define NCO 128
#define EPS 1e-5f
// log2(e) / sqrt(128)
#define ALPHA 0.12752269f

__device__ __forceinline__ unsigned short f2bf(float f) {
  union { float f; unsigned u; } v; v.f = f;
  unsigned r = v.u + 0x7FFFu + ((v.u >> 16) & 1u);
  return (unsigned short)(r >> 16);
}
__device__ __forceinline__ float bf2f(unsigned short h) {
  union { unsigned u; float f; } v; v.u = ((unsigned)h) << 16;
  return v.f;
}
__device__ __forceinline__ unsigned cvtpk_bf16(float lo, float hi) {
  unsigned r;
  asm("v_cvt_pk_bf16_f32 %0, %1, %2" : "=v"(r) : "v"(lo), "v"(hi));
  return r;
}
__device__ __forceinline__ void gload16(const void* g, void* l) {
  __builtin_amdgcn_global_load_lds(
      (const __attribute__((address_space(1))) unsigned*)g,
      (__attribute__((address_space(3))) unsigned*)l, 16, 0, 0);
}

// ---------------------------------------------------------------------------
// MFMA 1x1 conv + BN(eval) + ReLU for BOTH modalities (zz&1 = batch,
// zz>>1 = modality). Block = 128p x 128co, BK = 64.
// (byte-identical to round 4/5 — verified passing)
// ---------------------------------------------------------------------------
__global__ __launch_bounds__(256) void proj_mfma(
    const float* __restrict__ Xl, const float* __restrict__ Xi,
    const float* __restrict__ Wl, const float* __restrict__ Wi,
    const float* __restrict__ lgm, const float* __restrict__ lbt,
    const float* __restrict__ lmn, const float* __restrict__ lvr,
    const float* __restrict__ igm, const float* __restrict__ ibt,
    const float* __restrict__ imn, const float* __restrict__ ivr,
    unsigned short* __restrict__ Lp, unsigned short* __restrict__ Ip,
    unsigned short* __restrict__ Vg)
{
  __shared__ __align__(16) char smem[36352];
  float* sc_l = (float*)(smem + 35328);
  float* sh_l = (float*)(smem + 35840);

  const int t = threadIdx.x;
  const int w = t >> 6, l = t & 63, l15 = l & 15, g = l >> 4;
  const int zz = blockIdx.y, b = zz & 1, mod = zz >> 1;
  const int pb = blockIdx.x * 128;

  const float* Xg = mod ? Xi : Xl;
  const float* Wg = mod ? Wi : Wl;
  const int Cin = mod ? 512 : 256;
  unsigned short* outp = mod ? Ip : Lp;

  if (t < 128) {
    const float* G = mod ? igm : lgm;
    const float* Bt = mod ? ibt : lbt;
    const float* M = mod ? imn : lmn;
    const float* V = mod ? ivr : lvr;
    float s = G[t] / sqrtf(V[t] + EPS);
    sc_l[t] = s;
    sh_l[t] = Bt[t] - M[t] * s;
  }

  f32x4 o[2][8];
#pragma unroll
  for (int qt = 0; qt < 2; ++qt)
#pragma unroll
    for (int nt = 0; nt < 8; ++nt) o[qt][nt] = (f32x4){0.f, 0.f, 0.f, 0.f};

  uint2 xr[8], wr[8];
  auto load_tiles = [&](int s) {
    int cc = s * 64;
#pragma unroll
    for (int i = 0; i < 8; ++i) {
      int e = t + 256 * i;
      int c = e >> 5, p4 = e & 31;
      f32x4 x = *(const f32x4*)(Xg + ((size_t)(b * Cin + cc + c)) * P_TOT + pb + p4 * 4);
      xr[i].x = cvtpk_bf16(x[0], x[1]);
      xr[i].y = cvtpk_bf16(x[2], x[3]);
    }
#pragma unroll
    for (int i = 0; i < 8; ++i) {
      int e = t + 256 * i;
      int co = e >> 4, c4 = e & 15;
      f32x4 wv = *(const f32x4*)(Wg + (size_t)co * Cin + cc + c4 * 4);
      wr[i].x = cvtpk_bf16(wv[0], wv[1]);
      wr[i].y = cvtpk_bf16(wv[2], wv[3]);
    }
  };

  load_tiles(0);
  const int nsteps = Cin >> 6;
  for (int s = 0; s < nsteps; ++s) {
    __syncthreads();
#pragma unroll
    for (int i = 0; i < 8; ++i) {
      int e = t + 256 * i;
      int c = e >> 5, p4 = e & 31;
      *(uint2*)(smem + c * 264 + p4 * 8) = xr[i];
    }
#pragma unroll
    for (int i = 0; i < 8; ++i) {
      int e = t + 256 * i;
      int co = e >> 4, c4 = e & 15;
      *(uint2*)(smem + 16896 + co * 144 + c4 * 8) = wr[i];
    }
    if (s + 1 < nsteps) load_tiles(s + 1);
    __syncthreads();

#pragma unroll
    for (int kkc = 0; kkc < 2; ++kkc) {
      short8 a[2];
#pragma unroll
      for (int qt = 0; qt < 2; ++qt) {
        const char* ab = smem + (kkc * 32 + g * 8) * 264 + (w * 32 + qt * 16 + l15) * 2;
        union { unsigned uu[4]; short8 v; } cv;
#pragma unroll
        for (int e2 = 0; e2 < 4; ++e2) {
          unsigned lo = *(const unsigned short*)(ab + (2 * e2) * 264);
          unsigned hi = *(const unsigned short*)(ab + (2 * e2 + 1) * 264);
          cv.uu[e2] = lo | (hi << 16);
        }
        a[qt] = cv.v;
      }
#pragma unroll
      for (int nt = 0; nt < 8; ++nt) {
        short8 wf = *(const short8*)(smem + 16896 + (nt * 16 + l15) * 144 + kkc * 64 + g * 16);
        o[0][nt] = __builtin_amdgcn_mfma_f32_16x16x32_bf16(a[0], wf, o[0][nt], 0, 0, 0);
        o[1][nt] = __builtin_amdgcn_mfma_f32_16x16x32_bf16(a[1], wf, o[1][nt], 0, 0, 0);
      }
    }
  }

  __syncthreads();
#pragma unroll
  for (int nt = 0; nt < 8; ++nt) {
    float scv = sc_l[nt * 16 + l15];
    float shv = sh_l[nt * 16 + l15];
#pragma unroll
    for (int qt = 0; qt < 2; ++qt)
#pragma unroll
      for (int r = 0; r < 4; ++r) {
        int p = w * 32 + qt * 16 + 4 * g + r;
        float y = fmaxf(fmaf(o[qt][nt][r], scv, shv), 0.f);
        *(unsigned short*)(smem + p * 272 + (nt * 16 + l15) * 2) = f2bf(y);
      }
  }
  __syncthreads();
  {
    int p = t >> 1, half = t & 1;
    const char* Tb = smem + p * 272 + half * 128;
    unsigned short* ob = outp + ((size_t)b * P_TOT + pb + p) * NCO + half * 64;
#pragma unroll
    for (int i = 0; i < 8; ++i)
      *(uint4*)(ob + i * 8) = *(const uint4*)(Tb + i * 16);
  }
  if (mod == 0) {
    int co = t & 127, ph = t >> 7;
    unsigned short* vb = Vg + ((size_t)b * NCO + co) * P_TOT + pb + ph * 64;
    unsigned pkv[32];
#pragma unroll
    for (int j2 = 0; j2 < 32; ++j2) {
      unsigned lo = *(const unsigned short*)(smem + (ph * 64 + 2 * j2) * 272 + co * 2);
      unsigned hi = *(const unsigned short*)(smem + (ph * 64 + 2 * j2 + 1) * 272 + co * 2);
      pkv[j2] = lo | (hi << 16);
    }
#pragma unroll
    for (int i = 0; i < 8; ++i)
      *(uint4*)(vb + i * 8) = *(const uint4*)&pkv[i * 4];
  }
}

// ---------------------------------------------------------------------------
// Block-diagonal flash attention + blend. Same per-tile math as round 5;
// structural change: 512 threads = 2 wave-groups of 4. Group h processes
// k-tiles [h*16, h*16+16) with its own K/V double-buffered LDS region
// (64 KB each, 128 KB total) -> 8 waves/CU = 2 waves/SIMD latency hiding.
// End: in-LDS flash combine (group1 deposits raw O/m/lsum partials, group0
// merges in-register), then blend + coalesced transposed store.
// ---------------------------------------------------------------------------
__global__ __launch_bounds__(512) void attn_kernel(
    const unsigned short* __restrict__ Lp,  // [B][P][128] bf16 (K rows)
    const unsigned short* __restrict__ Ip,  // [B][P][128] bf16 (Q rows)
    const unsigned short* __restrict__ Vg,  // [B][128][P] bf16 (V cols)
    const float* __restrict__ mw,           // [2]
    float* __restrict__ out)                // [B][128][P] f32
{
  // main: [hb, hb+32768) K dbuf, [hb+32768, hb+65536) V dbuf (hb = half*65536)
  // merge (after main loop): Tp f32 [128][132] @ 0 (67584 B),
  //   m1a f32[128] @ 67584, l1a f32[128] @ 68096
  // epilogue: Tp reused for blended [c][q] tile
  __shared__ __align__(16) char smem[131072];

  const int t = threadIdx.x;
  const int half = t >> 8;       // k-half this wave-group owns
  const int t2 = t & 255;        // index within group
  const int w = t2 >> 6, l = t & 63;
  const int l15 = l & 15, g = l >> 4;
  const int hb = half << 16;
  // XCD swizzle: gid%8 == chunk (all blocks of a chunk share one XCD's L2)
  const int gid = blockIdx.x;
  const int bx = gid >> 4;
  const int chunk = gid & 7;
  const int b = (gid >> 3) & 1;
  const int pq0 = chunk * 2048 + bx * 128;
  const int qw = pq0 + w * 32;

  short8 qf[2][4];
#pragma unroll
  for (int qt = 0; qt < 2; ++qt)
#pragma unroll
    for (int kkc = 0; kkc < 4; ++kkc)
      qf[qt][kkc] = *(const short8*)(Ip +
          ((size_t)b * P_TOT + qw + qt * 16 + l15) * NCO + kkc * 32 + g * 8);

  const char* srcK[4];
  const char* srcV[4];
  int ldsOff[4];
#pragma unroll
  for (int i = 0; i < 4; ++i) {
    int pos = (w * 4 + i) * 4 + (l >> 4);
    int nt = pos >> 4, gp = (pos >> 2) & 3, rr = pos & 3;
    int kp = (nt >> 1) * 32 + gp * 8 + (nt & 1) * 4 + rr;
    srcK[i] = (const char*)Lp +
              ((size_t)b * P_TOT + chunk * 2048 + half * 1024 + kp) * 256 +
              (((l & 15) * 16) ^ ((pos & 7) << 4));
    int c = (w * 4 + i) * 8 + (l >> 3);
    srcV[i] = (const char*)Vg +
              (((size_t)(b * NCO + c)) * P_TOT + chunk * 2048 + half * 1024) * 2 +
              (((l & 7) * 16) ^ ((c & 7) << 4));
    ldsOff[i] = hb + (w * 4 + i) * 1024;
  }

  float m_[2] = {-1e30f, -1e30f}, lsum[2] = {0.f, 0.f};
  f32x4 o[2][8];
#pragma unroll
  for (int qt = 0; qt < 2; ++qt)
#pragma unroll
    for (int ct = 0; ct < 8; ++ct) o[qt][ct] = (f32x4){0.f, 0.f, 0.f, 0.f};

#pragma unroll
  for (int i = 0; i < 4; ++i) {
    gload16(srcK[i], smem + ldsOff[i]);
    gload16(srcV[i], smem + 32768 + ldsOff[i]);
  }
  __syncthreads();

  int cur = 0;
  for (int kt = 0; kt < 16; ++kt) {
    if (kt + 1 < 16) {
#pragma unroll
      for (int i = 0; i < 4; ++i) {
        gload16(srcK[i] + (size_t)(kt + 1) * 16384,
                smem + (cur ^ 1) * 16384 + ldsOff[i]);
        gload16(srcV[i] + (size_t)(kt + 1) * 128,
                smem + 32768 + (cur ^ 1) * 16384 + ldsOff[i]);
      }
    }
    const char* Kb = smem + hb + cur * 16384;
    const char* Vb = smem + hb + 32768 + cur * 16384;

    f32x4 s[2][4];
#pragma unroll
    for (int qt = 0; qt < 2; ++qt)
#pragma unroll
      for (int nt = 0; nt < 4; ++nt) s[qt][nt] = (f32x4){0.f, 0.f, 0.f, 0.f};
#pragma unroll
    for (int kkc = 0; kkc < 4; ++kkc) {
#pragma unroll
      for (int nt = 0; nt < 4; ++nt) {
        short8 kf = *(const short8*)(Kb + (nt * 16 + l15) * 256 +
                        ((kkc * 64 + g * 16) ^ ((l15 & 7) << 4)));
        s[0][nt] = __builtin_amdgcn_mfma_f32_16x16x32_bf16(kf, qf[0][kkc], s[0][nt], 0, 0, 0);
        s[1][nt] = __builtin_amdgcn_mfma_f32_16x16x32_bf16(kf, qf[1][kkc], s[1][nt], 0, 0, 0);
      }
    }

    unsigned pk[2][4][2];
    float f_[2];
    int upd[2];
#pragma unroll
    for (int qt = 0; qt < 2; ++qt) {
      float v0 = fmaxf(fmaxf(s[qt][0][0], s[qt][0][1]), fmaxf(s[qt][0][2], s[qt][0][3]));
      float v1 = fmaxf(fmaxf(s[qt][1][0], s[qt][1][1]), fmaxf(s[qt][1][2], s[qt][1][3]));
      float v2 = fmaxf(fmaxf(s[qt][2][0], s[qt][2][1]), fmaxf(s[qt][2][2], s[qt][2][3]));
      float v3 = fmaxf(fmaxf(s[qt][3][0], s[qt][3][1]), fmaxf(s[qt][3][2], s[qt][3][3]));
      float v = fmaxf(fmaxf(v0, v1), fmaxf(v2, v3));
      v = fmaxf(v, __shfl_xor(v, 16));
      v = fmaxf(v, __shfl_xor(v, 32));
      float pm = v * ALPHA;
      upd[qt] = __any(pm > m_[qt] + 8.f);  // T13 defer-rescale
      float mn = m_[qt];
      if (upd[qt]) {
        mn = fmaxf(m_[qt], pm);
        f_[qt] = __builtin_amdgcn_exp2f(m_[qt] - mn);
        m_[qt] = mn;
      } else {
        f_[qt] = 1.f;
      }
      float ps = 0.f;
#pragma unroll
      for (int nt = 0; nt < 4; ++nt) {
#pragma unroll
        for (int r = 0; r < 4; ++r) {
          float p = __builtin_amdgcn_exp2f(s[qt][nt][r] * ALPHA - mn);
          s[qt][nt][r] = p;
          ps += p;
        }
        pk[qt][nt][0] = cvtpk_bf16(s[qt][nt][0], s[qt][nt][1]);
        pk[qt][nt][1] = cvtpk_bf16(s[qt][nt][2], s[qt][nt][3]);
      }
      ps += __shfl_xor(ps, 16);
      ps += __shfl_xor(ps, 32);
      lsum[qt] = lsum[qt] * f_[qt] + ps;
    }

#pragma unroll
    for (int qt = 0; qt < 2; ++qt)
      if (upd[qt]) {
#pragma unroll
        for (int r = 0; r < 4; ++r) {
          float fb = __shfl(f_[qt], 20 * g + r);
#pragma unroll
          for (int ct = 0; ct < 8; ++ct) o[qt][ct][r] *= fb;
        }
      }

#pragma unroll
    for (int kk2 = 0; kk2 < 2; ++kk2) {
      short8 af[2];
#pragma unroll
      for (int qt = 0; qt < 2; ++qt) {
        union { unsigned u[4]; short8 v; } x;
        x.u[0] = pk[qt][2 * kk2][0];
        x.u[1] = pk[qt][2 * kk2][1];
        x.u[2] = pk[qt][2 * kk2 + 1][0];
        x.u[3] = pk[qt][2 * kk2 + 1][1];
        af[qt] = x.v;
      }
#pragma unroll
      for (int ct = 0; ct < 8; ++ct) {
        short8 vf = *(const short8*)(Vb + (ct * 16 + l15) * 128 +
                        ((kk2 * 64 + g * 16) ^ ((l15 & 7) << 4)));
        o[0][ct] = __builtin_amdgcn_mfma_f32_16x16x32_bf16(af[0], vf, o[0][ct], 0, 0, 0);
        o[1][ct] = __builtin_amdgcn_mfma_f32_16x16x32_bf16(af[1], vf, o[1][ct], 0, 0, 0);
      }
    }
    __syncthreads();
    cur ^= 1;
  }

  // ---- flash combine across the two k-halves (in LDS, raw partials)
  float* Tp = (float*)smem;               // [128][132] f32
  float* m1a = (float*)(smem + 67584);    // [128]
  float* l1a = (float*)(smem + 68096);    // [128]

  if (half == 1) {
#pragma unroll
    for (int qt = 0; qt < 2; ++qt) {
      int qb = w * 32 + qt * 16 + 4 * g;
#pragma unroll
      for (int ct = 0; ct < 8; ++ct) {
        int c = ct * 16 + l15;
        *(f32x4*)&Tp[c * 132 + qb] = o[qt][ct];
      }
      if (g == 0) {
        m1a[w * 32 + qt * 16 + l15] = m_[qt];
        l1a[w * 32 + qt * 16 + l15] = lsum[qt];
      }
    }
  }
  __syncthreads();

  // modality softmax
  float a0 = mw[0], a1 = mw[1];
  float mx = fmaxf(a0, a1);
  float e0 = __builtin_amdgcn_exp2f((a0 - mx) * 1.442695041f);
  float e1 = __builtin_amdgcn_exp2f((a1 - mx) * 1.442695041f);
  float w0m = e0 / (e0 + e1), w1m = e1 / (e0 + e1);

  if (half == 0) {
#pragma unroll
    for (int qt = 0; qt < 2; ++qt) {
      int qb = w * 32 + qt * 16 + 4 * g;
      f32x4 m1v = *(const f32x4*)&m1a[qb];
      f32x4 l1v = *(const f32x4*)&l1a[qb];
      float A[4], Bc[4];
#pragma unroll
      for (int r = 0; r < 4; ++r) {
        float m0r = __shfl(m_[qt], 20 * g + r);
        float l0r = __shfl(lsum[qt], 20 * g + r);
        float M = fmaxf(m0r, m1v[r]);
        float w0h = __builtin_amdgcn_exp2f(m0r - M);
        float w1h = __builtin_amdgcn_exp2f(m1v[r] - M);
        float L = w0h * l0r + w1h * l1v[r];
        A[r] = w1m * w0h / L;
        Bc[r] = w1m * w1h / L;
      }
#pragma unroll
      for (int ct = 0; ct < 8; ++ct) {
        int c = ct * 16 + l15;
        f32x4 o1 = *(const f32x4*)&Tp[c * 132 + qb];
#pragma unroll
        for (int r = 0; r < 4; ++r)
          o[qt][ct][r] = A[r] * o[qt][ct][r] + Bc[r] * o1[r];
      }
    }
  }
  __syncthreads();

  if (half == 0) {  // blend with image_proj, write full [c][q] tile
#pragma unroll
    for (int qt = 0; qt < 2; ++qt) {
      int qb = w * 32 + qt * 16 + 4 * g;
#pragma unroll
      for (int ct = 0; ct < 8; ++ct) {
        int c = ct * 16 + l15;
        f32x4 v = o[qt][ct];
#pragma unroll
        for (int r = 0; r < 4; ++r) {
          float img = bf2f(Ip[((size_t)b * P_TOT + pq0 + qb + r) * NCO + c]);
          v[r] = w0m * img + v[r];
        }
        *(f32x4*)&Tp[c * 132 + qb] = v;
      }
    }
  }
  __syncthreads();
  {
    int cc = t >> 5;            // 0..15
    int q0 = (t & 31) * 4;      // 0..124
#pragma unroll
    for (int i2 = 0; i2 < 8; ++i2) {
      int c = cc + i2 * 16;
      float* Ob = out + ((size_t)b * NCO + c) * P_TOT + pq0 + q0;
      *(f32x4*)Ob = *(const f32x4*)&Tp[c * 132 + q0];
    }
  }
}

extern "C" void kernel_launch(void* const* d_in, const int* in_sizes, int n_in,
                              void* d_out, int out_size, void* d_ws, size_t ws_size,
                              hipStream_t stream) {
  const float* lidar = (const float*)d_in[0];
  const float* image = (const float*)d_in[1];
  const float* lw = (const float*)d_in[2];
  const float* lg = (const float*)d_in[3];
  const float* lb = (const float*)d_in[4];
  const float* lm = (const float*)d_in[5];
  const float* lv = (const float*)d_in[6];
  const float* iw = (const float*)d_in[7];
  const float* ig = (const float*)d_in[8];
  const float* ibt = (const float*)d_in[9];
  const float* im = (const float*)d_in[10];
  const float* iv = (const float*)d_in[11];
  const float* mw = (const float*)d_in[12];

  unsigned short* Lp = (unsigned short*)d_ws;            // [2][16384][128] bf16
  unsigned short* Ip = Lp + (size_t)2 * P_TOT * NCO;     // [2][16384][128] bf16
  unsigned short* Vg = Ip + (size_t)2 * P_TOT * NCO;     // [2][128][16384] bf16

  dim3 gp(P_TOT / 128, 4);
  proj_mfma<<<gp, 256, 0, stream>>>(lidar, image, lw, iw,
                                    lg, lb, lm, lv, ig, ibt, im, iv,
                                    Lp, Ip, Vg);

  attn_kernel<<<dim3(256), 512, 0, stream>>>(Lp, Ip, Vg, mw, (float*)d_out);
}